// Round 1
// baseline (466.119 us; speedup 1.0000x reference)
//
#include <hip/hip_runtime.h>

#define TPB 256

// ---------------------------------------------------------------------------
// Dedup + degree + in-count. bitmap over n*n bits: first thread to set a
// (row,col) bit is the "winner" (distinct edge). deg[r] = #distinct cols per
// row (self handled later). cnt[c] = total in-edges (duplicates kept - GAT
// softmax uses the raw edge list).
// ---------------------------------------------------------------------------
__global__ void dedup_count_kernel(const int* __restrict__ edge, int E, int n,
                                   unsigned int* __restrict__ bitmap,
                                   int* __restrict__ cnt, int* __restrict__ deg,
                                   int* __restrict__ flags) {
    int e = blockIdx.x * blockDim.x + threadIdx.x;
    if (e >= E) return;
    int r = edge[e];
    int c = edge[E + e];
    unsigned long long key = (unsigned long long)r * (unsigned long long)n + (unsigned long long)c;
    unsigned int w = (unsigned int)(key >> 5);
    unsigned int b = 1u << (unsigned int)(key & 31ULL);
    unsigned int old = atomicOr(&bitmap[w], b);
    int win = (old & b) ? 0 : 1;
    flags[e] = win;
    if (win) atomicAdd(&deg[r], 1);
    atomicAdd(&cnt[c], 1);
}

// ---------------------------------------------------------------------------
// Single-block exclusive scan of (cnt[i]+1) -> offsets; self-loop edge placed
// at the head of each dst segment; fill[i] starts after it.
// ---------------------------------------------------------------------------
__global__ void scan_kernel(const int* __restrict__ cnt, int* __restrict__ offsets,
                            int* __restrict__ fill, int* __restrict__ csr, int n) {
    __shared__ int sh[1024];
    __shared__ int carry_sh;
    if (threadIdx.x == 0) carry_sh = 0;
    __syncthreads();
    int nch = (n + 1023) / 1024;
    for (int ch = 0; ch < nch; ch++) {
        int i = ch * 1024 + (int)threadIdx.x;
        int v = (i < n) ? (cnt[i] + 1) : 0;
        sh[threadIdx.x] = v;
        __syncthreads();
        for (int off = 1; off < 1024; off <<= 1) {
            int t = (threadIdx.x >= (unsigned)off) ? sh[threadIdx.x - off] : 0;
            __syncthreads();
            sh[threadIdx.x] += t;
            __syncthreads();
        }
        int incl = sh[threadIdx.x] + carry_sh;
        if (i < n) {
            int excl = incl - v;
            offsets[i] = excl;
            fill[i]    = excl + 1;   // slot 0 of the segment = self loop
            csr[excl]  = i;          // self-loop src
        }
        __syncthreads();
        if (threadIdx.x == 1023) carry_sh = incl;
        __syncthreads();
    }
    if (threadIdx.x == 0) offsets[n] = carry_sh;   // = E + n
}

__global__ void scatter_kernel(const int* __restrict__ edge, int* __restrict__ fill,
                               int* __restrict__ csr, int E) {
    int e = blockIdx.x * blockDim.x + threadIdx.x;
    if (e >= E) return;
    int r = edge[e];
    int c = edge[E + e];
    int pos = atomicAdd(&fill[c], 1);
    csr[pos] = r;
}

// ---------------------------------------------------------------------------
// h = x @ W  (per node), plus per-head attention logits e_src/e_dst.
// W, a_src, a_dst staged in LDS. IN<=32, HC<=32, C=4.
// ---------------------------------------------------------------------------
__global__ void transform_kernel(const float* __restrict__ x, const float* __restrict__ W,
                                 const float* __restrict__ asrc, const float* __restrict__ adst,
                                 int n, int IN, int H, int C,
                                 float* __restrict__ h, float* __restrict__ es,
                                 float* __restrict__ ed) {
    extern __shared__ float sh[];
    int HC = H * C;
    float* sW = sh;
    float* sa = sh + IN * HC;
    float* sd = sa + HC;
    for (int i = threadIdx.x; i < IN * HC; i += blockDim.x) sW[i] = W[i];
    for (int i = threadIdx.x; i < HC; i += blockDim.x) { sa[i] = asrc[i]; sd[i] = adst[i]; }
    __syncthreads();
    int node = blockIdx.x * blockDim.x + threadIdx.x;
    if (node >= n) return;
    float xv[32];
    for (int k = 0; k < IN; k++) xv[k] = x[(size_t)node * IN + k];
    for (int hd = 0; hd < H; hd++) {
        float e1 = 0.f, e2 = 0.f;
        for (int c = 0; c < C; c++) {
            int o = hd * C + c;
            float acc = 0.f;
            for (int k = 0; k < IN; k++) acc += xv[k] * sW[k * HC + o];
            h[(size_t)node * HC + o] = acc;
            e1 += acc * sa[o];
            e2 += acc * sd[o];
        }
        es[(size_t)node * H + hd] = e1;
        ed[(size_t)node * H + hd] = e2;
    }
}

// ---------------------------------------------------------------------------
// Segment softmax + aggregation, one thread per (dst, head). Two passes over
// the incoming-edge segment: (1) max, (2) fused exp-sum + weighted h-sum.
// Epilogue: /denom, +bias, relu. C hardcoded 4.
// ---------------------------------------------------------------------------
__global__ void aggregate_kernel(const int* __restrict__ offsets, const int* __restrict__ csr,
                                 const float* __restrict__ h, const float* __restrict__ es,
                                 const float* __restrict__ ed, const float* __restrict__ bias,
                                 int n, int H, float* __restrict__ xout) {
    int tid = blockIdx.x * blockDim.x + threadIdx.x;
    if (tid >= n * H) return;
    int node = tid / H;
    int hd   = tid % H;
    int beg = offsets[node], end = offsets[node + 1];
    float edv = ed[(size_t)node * H + hd];
    float m = -1e30f;
    for (int k = beg; k < end; k++) {
        int s = csr[k];
        float e = es[(size_t)s * H + hd] + edv;
        e = (e > 0.f) ? e : 0.2f * e;
        m = fmaxf(m, e);
    }
    int HC = H * 4;
    float denom = 0.f;
    float acc0 = 0.f, acc1 = 0.f, acc2 = 0.f, acc3 = 0.f;
    for (int k = beg; k < end; k++) {
        int s = csr[k];
        float e = es[(size_t)s * H + hd] + edv;
        e = (e > 0.f) ? e : 0.2f * e;
        float w = __expf(e - m);
        denom += w;
        const float* hp = &h[(size_t)s * HC + hd * 4];
        acc0 += w * hp[0];
        acc1 += w * hp[1];
        acc2 += w * hp[2];
        acc3 += w * hp[3];
    }
    float inv = 1.0f / denom;
    float* op = &xout[(size_t)node * HC + hd * 4];
    const float* bp = &bias[hd * 4];
    float v;
    v = acc0 * inv + bp[0]; op[0] = v > 0.f ? v : 0.f;
    v = acc1 * inv + bp[1]; op[1] = v > 0.f ? v : 0.f;
    v = acc2 * inv + bp[2]; op[2] = v > 0.f ? v : 0.f;
    v = acc3 * inv + bp[3]; op[3] = v > 0.f ? v : 0.f;
}

// ---------------------------------------------------------------------------
// s[r] += x6[c] over winning (distinct) edges.
// ---------------------------------------------------------------------------
__global__ void accum_kernel(const int* __restrict__ edge, const int* __restrict__ flags,
                             const float* __restrict__ x6, float* __restrict__ ssum, int E) {
    int e = blockIdx.x * blockDim.x + threadIdx.x;
    if (e >= E) return;
    if (!flags[e]) return;
    int r = edge[e];
    int c = edge[E + e];
    for (int j = 0; j < 8; j++)
        atomicAdd(&ssum[(size_t)r * 8 + j], x6[(size_t)c * 8 + j]);
}

// ---------------------------------------------------------------------------
// out[i] = (x6[i]·s_i + s_i·lin2_w)/deg_i + x1[i,0]
// s_i / deg_i get the diagonal contribution iff edge (i,i) wasn't present.
// ---------------------------------------------------------------------------
__global__ void final_kernel(const float* __restrict__ x6, const float* __restrict__ ssum,
                             const int* __restrict__ deg, const unsigned int* __restrict__ bitmap,
                             const float* __restrict__ x1, const float* __restrict__ lw,
                             float* __restrict__ out, int n) {
    int i = blockIdx.x * blockDim.x + threadIdx.x;
    if (i >= n) return;
    unsigned long long key = (unsigned long long)i * (unsigned long long)n + (unsigned long long)i;
    bool selfSet = (bitmap[(size_t)(key >> 5)] >> (unsigned int)(key & 31ULL)) & 1u;
    float d = (float)(deg[i] + (selfSet ? 0 : 1));
    float r2 = 0.f, gs = 0.f;
    for (int j = 0; j < 8; j++) {
        float xv = x6[(size_t)i * 8 + j];
        float sv = ssum[(size_t)i * 8 + j] + (selfSet ? 0.f : xv);
        r2 += sv * xv;
        gs += sv * lw[j];
    }
    out[i] = (r2 + gs) / d + x1[(size_t)i * 10];
}

extern "C" void kernel_launch(void* const* d_in, const int* in_sizes, int n_in,
                              void* d_out, int out_size, void* d_ws, size_t ws_size,
                              hipStream_t stream) {
    const float* x1  = (const float*)d_in[0];
    // x2 (d_in[1]) is unused by the reference
    const int*   edge = (const int*)d_in[2];
    const float* W1  = (const float*)d_in[4];
    const float* as1 = (const float*)d_in[5];
    const float* ad1 = (const float*)d_in[6];
    const float* b1  = (const float*)d_in[7];
    const float* W2  = (const float*)d_in[8];
    const float* as2 = (const float*)d_in[9];
    const float* ad2 = (const float*)d_in[10];
    const float* b2  = (const float*)d_in[11];
    const float* W3  = (const float*)d_in[12];
    const float* as3 = (const float*)d_in[13];
    const float* ad3 = (const float*)d_in[14];
    const float* b3  = (const float*)d_in[15];
    const float* lw  = (const float*)d_in[16];
    float* out = (float*)d_out;

    const int n = in_sizes[0] / 10;     // 10000
    const int E = in_sizes[2] / 2;      // 320000

    // ---- workspace layout (4B units) ----
    size_t BW = ((size_t)n * (size_t)n + 31) / 32;   // bitmap words
    char* p = (char*)d_ws;
    unsigned int* bitmap = (unsigned int*)p; p += BW * 4;
    int*   cnt     = (int*)p;   p += (size_t)n * 4;
    int*   deg     = (int*)p;   p += (size_t)n * 4;
    float* ssum    = (float*)p; p += (size_t)n * 8 * 4;
    size_t zbytes  = (size_t)(p - (char*)d_ws);      // zero-init region ends here
    int*   fill    = (int*)p;   p += (size_t)n * 4;
    int*   flags   = (int*)p;   p += (size_t)E * 4;
    int*   offsets = (int*)p;   p += (size_t)(n + 1) * 4;
    int*   csr     = (int*)p;   p += (size_t)(E + n) * 4;
    float* h1  = (float*)p; p += (size_t)n * 32 * 4;
    float* es1 = (float*)p; p += (size_t)n * 8 * 4;
    float* ed1 = (float*)p; p += (size_t)n * 8 * 4;
    float* x3  = (float*)p; p += (size_t)n * 32 * 4;
    float* h2  = (float*)p; p += (size_t)n * 16 * 4;
    float* es2 = (float*)p; p += (size_t)n * 4 * 4;
    float* ed2 = (float*)p; p += (size_t)n * 4 * 4;
    float* x4  = (float*)p; p += (size_t)n * 16 * 4;
    float* h3  = (float*)p; p += (size_t)n * 8 * 4;
    float* es3 = (float*)p; p += (size_t)n * 2 * 4;
    float* ed3 = (float*)p; p += (size_t)n * 2 * 4;
    float* x6  = (float*)p; p += (size_t)n * 8 * 4;

    hipMemsetAsync(d_ws, 0, zbytes, stream);

    int ebl = (E + TPB - 1) / TPB;
    int nbl = (n + TPB - 1) / TPB;

    dedup_count_kernel<<<ebl, TPB, 0, stream>>>(edge, E, n, bitmap, cnt, deg, flags);
    scan_kernel<<<1, 1024, 0, stream>>>(cnt, offsets, fill, csr, n);
    scatter_kernel<<<ebl, TPB, 0, stream>>>(edge, fill, csr, E);

    // layer 1: IN=10, H=8, C=4
    transform_kernel<<<nbl, TPB, (10 * 32 + 2 * 32) * sizeof(float), stream>>>(
        x1, W1, as1, ad1, n, 10, 8, 4, h1, es1, ed1);
    aggregate_kernel<<<(n * 8 + TPB - 1) / TPB, TPB, 0, stream>>>(
        offsets, csr, h1, es1, ed1, b1, n, 8, x3);

    // layer 2: IN=32, H=4, C=4
    transform_kernel<<<nbl, TPB, (32 * 16 + 2 * 16) * sizeof(float), stream>>>(
        x3, W2, as2, ad2, n, 32, 4, 4, h2, es2, ed2);
    aggregate_kernel<<<(n * 4 + TPB - 1) / TPB, TPB, 0, stream>>>(
        offsets, csr, h2, es2, ed2, b2, n, 4, x4);

    // layer 3: IN=16, H=2, C=4
    transform_kernel<<<nbl, TPB, (16 * 8 + 2 * 8) * sizeof(float), stream>>>(
        x4, W3, as3, ad3, n, 16, 2, 4, h3, es3, ed3);
    aggregate_kernel<<<(n * 2 + TPB - 1) / TPB, TPB, 0, stream>>>(
        offsets, csr, h3, es3, ed3, b3, n, 2, x6);

    // scoring epilogue
    accum_kernel<<<ebl, TPB, 0, stream>>>(edge, flags, x6, ssum, E);
    final_kernel<<<nbl, TPB, 0, stream>>>(x6, ssum, deg, bitmap, x1, lw, out, n);
}

// Round 2
// 385.825 us; speedup vs baseline: 1.2081x; 1.2081x over previous
//
#include <hip/hip_runtime.h>

#define TPB 256

// ---------------------------------------------------------------------------
// Dedup + degree + in-count. bitmap over n*n bits: first thread to set a
// (row,col) bit is the "winner" (distinct edge). deg[r] = #distinct cols per
// row (self handled later). cnt[c] = total in-edges (duplicates kept - GAT
// softmax uses the raw edge list).
// ---------------------------------------------------------------------------
__global__ void dedup_count_kernel(const int* __restrict__ edge, int E, int n,
                                   unsigned int* __restrict__ bitmap,
                                   int* __restrict__ cnt, int* __restrict__ deg,
                                   int* __restrict__ flags) {
    int e = blockIdx.x * blockDim.x + threadIdx.x;
    if (e >= E) return;
    int r = edge[e];
    int c = edge[E + e];
    unsigned long long key = (unsigned long long)r * (unsigned long long)n + (unsigned long long)c;
    unsigned int w = (unsigned int)(key >> 5);
    unsigned int b = 1u << (unsigned int)(key & 31ULL);
    unsigned int old = atomicOr(&bitmap[w], b);
    int win = (old & b) ? 0 : 1;
    flags[e] = win;
    if (win) atomicAdd(&deg[r], 1);
    atomicAdd(&cnt[c], 1);
}

// ---------------------------------------------------------------------------
// Single-block exclusive scans:
//   phase 0: (cnt[i]+1) -> offsets (dst-CSR, self-loop at segment head)
//   phase 1: deg[i]     -> roffsets (row-CSR of distinct out-edges)
// ---------------------------------------------------------------------------
__global__ void scan_kernel(const int* __restrict__ cnt, const int* __restrict__ deg,
                            int* __restrict__ offsets, int* __restrict__ fill,
                            int* __restrict__ csr,
                            int* __restrict__ roffsets, int* __restrict__ rfill,
                            int n) {
    __shared__ int sh[1024];
    __shared__ int carry_sh;
    for (int phase = 0; phase < 2; phase++) {
        if (threadIdx.x == 0) carry_sh = 0;
        __syncthreads();
        int nch = (n + 1023) / 1024;
        for (int ch = 0; ch < nch; ch++) {
            int i = ch * 1024 + (int)threadIdx.x;
            int v = 0;
            if (i < n) v = (phase == 0) ? (cnt[i] + 1) : deg[i];
            sh[threadIdx.x] = v;
            __syncthreads();
            for (int off = 1; off < 1024; off <<= 1) {
                int t = (threadIdx.x >= (unsigned)off) ? sh[threadIdx.x - off] : 0;
                __syncthreads();
                sh[threadIdx.x] += t;
                __syncthreads();
            }
            int incl = sh[threadIdx.x] + carry_sh;
            if (i < n) {
                int excl = incl - v;
                if (phase == 0) {
                    offsets[i] = excl;
                    fill[i]    = excl + 1;   // slot 0 of the segment = self loop
                    csr[excl]  = i;          // self-loop src
                } else {
                    roffsets[i] = excl;
                    rfill[i]    = excl;
                }
            }
            __syncthreads();
            if (threadIdx.x == 1023) carry_sh = incl;
            __syncthreads();
        }
        if (threadIdx.x == 0) {
            if (phase == 0) offsets[n] = carry_sh;   // = E + n
            else            roffsets[n] = carry_sh;  // = #distinct edges
        }
        __syncthreads();
    }
}

// ---------------------------------------------------------------------------
// Scatter into dst-CSR (all edges) and row-CSR (winning/distinct edges).
// ---------------------------------------------------------------------------
__global__ void scatter_kernel(const int* __restrict__ edge, const int* __restrict__ flags,
                               int* __restrict__ fill, int* __restrict__ csr,
                               int* __restrict__ rfill, int* __restrict__ rcsr, int E) {
    int e = blockIdx.x * blockDim.x + threadIdx.x;
    if (e >= E) return;
    int r = edge[e];
    int c = edge[E + e];
    int pos = atomicAdd(&fill[c], 1);
    csr[pos] = r;
    if (flags[e]) {
        int rp = atomicAdd(&rfill[r], 1);
        rcsr[rp] = c;
    }
}

// ---------------------------------------------------------------------------
// h = x @ W  (per node), plus per-head attention logits e_src/e_dst.
// W, a_src, a_dst staged in LDS. IN<=32, HC<=32, C=4.
// ---------------------------------------------------------------------------
__global__ void transform_kernel(const float* __restrict__ x, const float* __restrict__ W,
                                 const float* __restrict__ asrc, const float* __restrict__ adst,
                                 int n, int IN, int H, int C,
                                 float* __restrict__ h, float* __restrict__ es,
                                 float* __restrict__ ed) {
    extern __shared__ float sh[];
    int HC = H * C;
    float* sW = sh;
    float* sa = sh + IN * HC;
    float* sd = sa + HC;
    for (int i = threadIdx.x; i < IN * HC; i += blockDim.x) sW[i] = W[i];
    for (int i = threadIdx.x; i < HC; i += blockDim.x) { sa[i] = asrc[i]; sd[i] = adst[i]; }
    __syncthreads();
    int node = blockIdx.x * blockDim.x + threadIdx.x;
    if (node >= n) return;
    float xv[32];
    for (int k = 0; k < IN; k++) xv[k] = x[(size_t)node * IN + k];
    for (int hd = 0; hd < H; hd++) {
        float e1 = 0.f, e2 = 0.f;
        for (int c = 0; c < C; c++) {
            int o = hd * C + c;
            float acc = 0.f;
            for (int k = 0; k < IN; k++) acc += xv[k] * sW[k * HC + o];
            h[(size_t)node * HC + o] = acc;
            e1 += acc * sa[o];
            e2 += acc * sd[o];
        }
        es[(size_t)node * H + hd] = e1;
        ed[(size_t)node * H + hd] = e2;
    }
}

// ---------------------------------------------------------------------------
// Segment softmax + aggregation, one thread per (dst, head). Two passes over
// the incoming-edge segment: (1) max, (2) fused exp-sum + weighted h-sum.
// Epilogue: /denom, +bias, relu. C hardcoded 4.
// ---------------------------------------------------------------------------
__global__ void aggregate_kernel(const int* __restrict__ offsets, const int* __restrict__ csr,
                                 const float* __restrict__ h, const float* __restrict__ es,
                                 const float* __restrict__ ed, const float* __restrict__ bias,
                                 int n, int H, float* __restrict__ xout) {
    int tid = blockIdx.x * blockDim.x + threadIdx.x;
    if (tid >= n * H) return;
    int node = tid / H;
    int hd   = tid % H;
    int beg = offsets[node], end = offsets[node + 1];
    float edv = ed[(size_t)node * H + hd];
    float m = -1e30f;
    for (int k = beg; k < end; k++) {
        int s = csr[k];
        float e = es[(size_t)s * H + hd] + edv;
        e = (e > 0.f) ? e : 0.2f * e;
        m = fmaxf(m, e);
    }
    int HC = H * 4;
    float denom = 0.f;
    float4 acc = make_float4(0.f, 0.f, 0.f, 0.f);
    for (int k = beg; k < end; k++) {
        int s = csr[k];
        float e = es[(size_t)s * H + hd] + edv;
        e = (e > 0.f) ? e : 0.2f * e;
        float w = __expf(e - m);
        denom += w;
        float4 hv = *(const float4*)&h[(size_t)s * HC + hd * 4];
        acc.x += w * hv.x;
        acc.y += w * hv.y;
        acc.z += w * hv.z;
        acc.w += w * hv.w;
    }
    float inv = 1.0f / denom;
    float* op = &xout[(size_t)node * HC + hd * 4];
    const float* bp = &bias[hd * 4];
    float v;
    v = acc.x * inv + bp[0]; op[0] = v > 0.f ? v : 0.f;
    v = acc.y * inv + bp[1]; op[1] = v > 0.f ? v : 0.f;
    v = acc.z * inv + bp[2]; op[2] = v > 0.f ? v : 0.f;
    v = acc.w * inv + bp[3]; op[3] = v > 0.f ? v : 0.f;
}

// ---------------------------------------------------------------------------
// Fused epilogue (gather, no atomics):
//   s_i = sum over distinct out-neighbors (row-CSR) of x6, + x6[i] if the
//         self-edge wasn't already present (diag fill).
//   out[i] = (x6[i]·s_i + s_i·lin2_w)/deg_i + x1[i,0]
// ---------------------------------------------------------------------------
__global__ void final_kernel(const float* __restrict__ x6,
                             const int* __restrict__ roffsets, const int* __restrict__ rcsr,
                             const unsigned int* __restrict__ bitmap,
                             const float* __restrict__ x1, const float* __restrict__ lw,
                             float* __restrict__ out, int n) {
    int i = blockIdx.x * blockDim.x + threadIdx.x;
    if (i >= n) return;
    unsigned long long key = (unsigned long long)i * (unsigned long long)n + (unsigned long long)i;
    bool selfSet = (bitmap[(size_t)(key >> 5)] >> (unsigned int)(key & 31ULL)) & 1u;
    int beg = roffsets[i], end = roffsets[i + 1];
    float d = (float)((end - beg) + (selfSet ? 0 : 1));
    const float4* x6v = (const float4*)x6;
    float4 me0 = x6v[(size_t)i * 2];
    float4 me1 = x6v[(size_t)i * 2 + 1];
    float4 s0, s1;
    if (selfSet) {
        s0 = make_float4(0.f, 0.f, 0.f, 0.f);
        s1 = make_float4(0.f, 0.f, 0.f, 0.f);
    } else {
        s0 = me0; s1 = me1;
    }
    for (int k = beg; k < end; k++) {
        int c = rcsr[k];
        float4 a = x6v[(size_t)c * 2];
        float4 b = x6v[(size_t)c * 2 + 1];
        s0.x += a.x; s0.y += a.y; s0.z += a.z; s0.w += a.w;
        s1.x += b.x; s1.y += b.y; s1.z += b.z; s1.w += b.w;
    }
    float r2 = s0.x * me0.x + s0.y * me0.y + s0.z * me0.z + s0.w * me0.w
             + s1.x * me1.x + s1.y * me1.y + s1.z * me1.z + s1.w * me1.w;
    float gs = s0.x * lw[0] + s0.y * lw[1] + s0.z * lw[2] + s0.w * lw[3]
             + s1.x * lw[4] + s1.y * lw[5] + s1.z * lw[6] + s1.w * lw[7];
    out[i] = (r2 + gs) / d + x1[(size_t)i * 10];
}

static inline size_t align16(size_t x) { return (x + 15) & ~(size_t)15; }

extern "C" void kernel_launch(void* const* d_in, const int* in_sizes, int n_in,
                              void* d_out, int out_size, void* d_ws, size_t ws_size,
                              hipStream_t stream) {
    const float* x1  = (const float*)d_in[0];
    // x2 (d_in[1]) is unused by the reference
    const int*   edge = (const int*)d_in[2];
    const float* W1  = (const float*)d_in[4];
    const float* as1 = (const float*)d_in[5];
    const float* ad1 = (const float*)d_in[6];
    const float* b1  = (const float*)d_in[7];
    const float* W2  = (const float*)d_in[8];
    const float* as2 = (const float*)d_in[9];
    const float* ad2 = (const float*)d_in[10];
    const float* b2  = (const float*)d_in[11];
    const float* W3  = (const float*)d_in[12];
    const float* as3 = (const float*)d_in[13];
    const float* ad3 = (const float*)d_in[14];
    const float* b3  = (const float*)d_in[15];
    const float* lw  = (const float*)d_in[16];
    float* out = (float*)d_out;

    const int n = in_sizes[0] / 10;     // 10000
    const int E = in_sizes[2] / 2;      // 320000

    // ---- workspace layout (16B aligned blocks) ----
    size_t BW = ((size_t)n * (size_t)n + 31) / 32;   // bitmap words
    char* p = (char*)d_ws;
    unsigned int* bitmap = (unsigned int*)p; p += align16(BW * 4);
    int*   cnt     = (int*)p;   p += align16((size_t)n * 4);
    int*   deg     = (int*)p;   p += align16((size_t)n * 4);
    size_t zbytes  = (size_t)(p - (char*)d_ws);      // zero-init region ends here
    int*   fill    = (int*)p;   p += align16((size_t)n * 4);
    int*   rfill   = (int*)p;   p += align16((size_t)n * 4);
    int*   flags   = (int*)p;   p += align16((size_t)E * 4);
    int*   offsets = (int*)p;   p += align16((size_t)(n + 1) * 4);
    int*   roffsets= (int*)p;   p += align16((size_t)(n + 1) * 4);
    int*   csr     = (int*)p;   p += align16((size_t)(E + n) * 4);
    int*   rcsr    = (int*)p;   p += align16((size_t)E * 4);
    float* h1  = (float*)p; p += align16((size_t)n * 32 * 4);
    float* es1 = (float*)p; p += align16((size_t)n * 8 * 4);
    float* ed1 = (float*)p; p += align16((size_t)n * 8 * 4);
    float* x3  = (float*)p; p += align16((size_t)n * 32 * 4);
    float* h2  = (float*)p; p += align16((size_t)n * 16 * 4);
    float* es2 = (float*)p; p += align16((size_t)n * 4 * 4);
    float* ed2 = (float*)p; p += align16((size_t)n * 4 * 4);
    float* x4  = (float*)p; p += align16((size_t)n * 16 * 4);
    float* h3  = (float*)p; p += align16((size_t)n * 8 * 4);
    float* es3 = (float*)p; p += align16((size_t)n * 2 * 4);
    float* ed3 = (float*)p; p += align16((size_t)n * 2 * 4);
    float* x6  = (float*)p; p += align16((size_t)n * 8 * 4);

    hipMemsetAsync(d_ws, 0, zbytes, stream);

    int ebl = (E + TPB - 1) / TPB;
    int nbl = (n + TPB - 1) / TPB;

    dedup_count_kernel<<<ebl, TPB, 0, stream>>>(edge, E, n, bitmap, cnt, deg, flags);
    scan_kernel<<<1, 1024, 0, stream>>>(cnt, deg, offsets, fill, csr, roffsets, rfill, n);
    scatter_kernel<<<ebl, TPB, 0, stream>>>(edge, flags, fill, csr, rfill, rcsr, E);

    // layer 1: IN=10, H=8, C=4
    transform_kernel<<<nbl, TPB, (10 * 32 + 2 * 32) * sizeof(float), stream>>>(
        x1, W1, as1, ad1, n, 10, 8, 4, h1, es1, ed1);
    aggregate_kernel<<<(n * 8 + TPB - 1) / TPB, TPB, 0, stream>>>(
        offsets, csr, h1, es1, ed1, b1, n, 8, x3);

    // layer 2: IN=32, H=4, C=4
    transform_kernel<<<nbl, TPB, (32 * 16 + 2 * 16) * sizeof(float), stream>>>(
        x3, W2, as2, ad2, n, 32, 4, 4, h2, es2, ed2);
    aggregate_kernel<<<(n * 4 + TPB - 1) / TPB, TPB, 0, stream>>>(
        offsets, csr, h2, es2, ed2, b2, n, 4, x4);

    // layer 3: IN=16, H=2, C=4
    transform_kernel<<<nbl, TPB, (16 * 8 + 2 * 8) * sizeof(float), stream>>>(
        x4, W3, as3, ad3, n, 16, 2, 4, h3, es3, ed3);
    aggregate_kernel<<<(n * 2 + TPB - 1) / TPB, TPB, 0, stream>>>(
        offsets, csr, h3, es3, ed3, b3, n, 2, x6);

    // fused scoring epilogue (gather over row-CSR, no atomics)
    final_kernel<<<nbl, TPB, 0, stream>>>(x6, roffsets, rcsr, bitmap, x1, lw, out, n);
}